// Round 1
// baseline (435.091 us; speedup 1.0000x reference)
//
#include <hip/hip_runtime.h>

typedef float floatx4 __attribute__((ext_vector_type(4)));
typedef __bf16 bfx8 __attribute__((ext_vector_type(8)));
typedef __bf16 bfx4 __attribute__((ext_vector_type(4)));

// Problem constants
constexpr int B_ = 2, S_ = 2048, H_ = 2048, NH_ = 16, NKV_ = 4, HD_ = 64;
constexpr int M_ = B_ * S_;               // 4096 rows
constexpr int NQKV_ = NH_ * HD_ + 2 * NKV_ * HD_; // 1536
constexpr int HQ_ = NH_ * HD_;            // 1024

// ---------------- kernel: fp32 -> bf16 cast (x4 vectorized) ----------------
__global__ __launch_bounds__(256) void cast_f32_bf16(const float* __restrict__ src,
                                                     __bf16* __restrict__ dst, int n4) {
  int i = blockIdx.x * 256 + threadIdx.x;
  if (i >= n4) return;
  float4 v = ((const float4*)src)[i];
  bfx4 o;
  o[0] = (__bf16)v.x; o[1] = (__bf16)v.y; o[2] = (__bf16)v.z; o[3] = (__bf16)v.w;
  ((bfx4*)dst)[i] = o;
}

// ---------------- kernel: transpose + cast: dst[n+off][k] = src[k][n] ----------------
__global__ __launch_bounds__(256) void transpose_cast(const float* __restrict__ src,
                                                      __bf16* __restrict__ dst,
                                                      int K, int N, int dstOff, int dstPitch) {
  __shared__ float tile[32][33];
  int n0 = blockIdx.x * 32, k0 = blockIdx.y * 32;
  int tx = threadIdx.x, ty = threadIdx.y; // block (32,8)
#pragma unroll
  for (int r = 0; r < 32; r += 8)
    tile[ty + r][tx] = src[(size_t)(k0 + ty + r) * N + n0 + tx];
  __syncthreads();
#pragma unroll
  for (int r = 0; r < 32; r += 8)
    dst[(size_t)(n0 + ty + r + dstOff) * dstPitch + k0 + tx] = (__bf16)tile[tx][ty + r];
}

// ---------------- kernel: bf16 MFMA GEMM. A: MxK row-major, Bt: NxK row-major, C: MxN fp32
// 128x128 block tile, BK=64, 4 waves in 2x2, each wave 64x64 (4x4 MFMA 16x16x32 tiles).
__global__ __launch_bounds__(256) void gemm_bf16_f32(const __bf16* __restrict__ A,
                                                     const __bf16* __restrict__ Bt,
                                                     float* __restrict__ C,
                                                     int M, int N, int K) {
  __shared__ __align__(16) __bf16 As[128][72]; // pad 64->72 (+16B): bank stride 4 -> 2-way (free)
  __shared__ __align__(16) __bf16 Bs[128][72];
  int wid = threadIdx.x >> 6, lane = threadIdx.x & 63;
  int l15 = lane & 15, quad = lane >> 4;
  int wm = (wid >> 1) * 64, wn = (wid & 1) * 64;
  int m0 = blockIdx.y * 128, n0 = blockIdx.x * 128;
  floatx4 acc[4][4] = {};
  for (int kb = 0; kb < K; kb += 64) {
#pragma unroll
    for (int i = 0; i < 4; i++) {
      int c = i * 256 + threadIdx.x;
      int r = c >> 3, col = (c & 7) * 8;
      *(bfx8*)&As[r][col] = *(const bfx8*)&A[(size_t)(m0 + r) * K + kb + col];
      *(bfx8*)&Bs[r][col] = *(const bfx8*)&Bt[(size_t)(n0 + r) * K + kb + col];
    }
    __syncthreads();
#pragma unroll
    for (int kk = 0; kk < 64; kk += 32) {
      bfx8 af[4], bfr[4];
#pragma unroll
      for (int mi = 0; mi < 4; mi++)
        af[mi] = *(const bfx8*)&As[wm + mi * 16 + l15][kk + quad * 8];
#pragma unroll
      for (int ni = 0; ni < 4; ni++)
        bfr[ni] = *(const bfx8*)&Bs[wn + ni * 16 + l15][kk + quad * 8];
#pragma unroll
      for (int mi = 0; mi < 4; mi++)
#pragma unroll
        for (int ni = 0; ni < 4; ni++)
          acc[mi][ni] = __builtin_amdgcn_mfma_f32_16x16x32_bf16(af[mi], bfr[ni], acc[mi][ni], 0, 0, 0);
    }
    __syncthreads();
  }
#pragma unroll
  for (int mi = 0; mi < 4; mi++)
#pragma unroll
    for (int ni = 0; ni < 4; ni++) {
      int row = m0 + wm + mi * 16 + quad * 4;
      int coln = n0 + wn + ni * 16 + l15;
#pragma unroll
      for (int r = 0; r < 4; r++)
        C[(size_t)(row + r) * N + coln] = acc[mi][ni][r];
    }
}

// ---------------- kernel: RMSNorm + RoPE on q/k, cast+layout for attention ----------------
// qkv fp32 [B*S][1536]. Outputs: Q [B][NH][S][HD] bf16, K [B][NKV][S][HD] bf16, VT [B][NKV][HD][S] bf16
__global__ __launch_bounds__(256) void norm_rope_kernel(const float* __restrict__ qkv,
                                                        const float* __restrict__ cosT,
                                                        const float* __restrict__ sinT,
                                                        const float* __restrict__ qw,
                                                        const float* __restrict__ kw,
                                                        __bf16* __restrict__ Qo,
                                                        __bf16* __restrict__ Ko,
                                                        __bf16* __restrict__ VTo) {
  int s = blockIdx.x, b = blockIdx.y;
  int wid = threadIdx.x >> 6, lane = threadIdx.x & 63;
  const float* rowp = qkv + (size_t)(b * S_ + s) * NQKV_;
  float c = cosT[s * HD_ + lane];
  float sn = sinT[s * HD_ + lane];
#pragma unroll
  for (int it = 0; it < 5; it++) {
    int hh = it * 4 + wid; // 0..15 q heads, 16..19 k heads (offset hh*64 works: 16*64==1024)
    float v = rowp[hh * 64 + lane];
    float ss = v * v;
#pragma unroll
    for (int off = 1; off < 64; off <<= 1) ss += __shfl_xor(ss, off);
    float rs = rsqrtf(ss * (1.0f / 64.0f) + 1e-6f);
    const float* w = (hh < 16) ? qw : kw;
    float nv = v * rs * w[lane];
    float other = __shfl_xor(nv, 32);
    float rot = (lane < 32) ? -other : other; // rotate_half
    float outv = nv * c + rot * sn;
    if (hh < 16)
      Qo[(((size_t)b * NH_ + hh) * S_ + s) * HD_ + lane] = (__bf16)outv;
    else
      Ko[(((size_t)b * NKV_ + (hh - 16)) * S_ + s) * HD_ + lane] = (__bf16)outv;
  }
  // V: wave wid handles kv head wid; transposed store for PV B-operand
  {
    float v = rowp[(20 + wid) * 64 + lane];
    VTo[(((size_t)b * NKV_ + wid) * HD_ + lane) * S_ + s] = (__bf16)v;
  }
}

// ---------------- kernel: flash attention (causal, GQA) ----------------
// grid (S/64, NH, B), block 256 (4 waves). Wave w owns q rows [qt*64+w*16, +16).
__global__ __launch_bounds__(256) void attn_kernel(const __bf16* __restrict__ Q,
                                                   const __bf16* __restrict__ Kc,
                                                   const __bf16* __restrict__ VT,
                                                   __bf16* __restrict__ Ob) {
  int qt = blockIdx.x, h = blockIdx.y, b = blockIdx.z;
  int wid = threadIdx.x >> 6, lane = threadIdx.x & 63;
  int l15 = lane & 15, quad = lane >> 4;
  int q0 = qt * 64 + wid * 16;
  int kvh = h >> 2; // N_REP = 4
  const __bf16* Qh = Q + (((size_t)b * NH_ + h) * S_ + q0) * HD_;
  const __bf16* Kh = Kc + (((size_t)b * NKV_ + kvh) * S_) * HD_;
  const __bf16* Vh = VT + (((size_t)b * NKV_ + kvh) * HD_) * S_;
  __shared__ __align__(16) __bf16 Pst[4][16][72]; // per-wave P staging (C-layout -> A-layout)
  __bf16 (*P)[72] = Pst[wid];

  bfx8 qf0, qf1;
  {
    const __bf16* qp = Qh + l15 * HD_ + quad * 8;
    qf0 = *(const bfx8*)qp;
    qf1 = *(const bfx8*)(qp + 32);
  }
  floatx4 oacc[4] = {};
  float mrow[4] = {-1e30f, -1e30f, -1e30f, -1e30f};
  float lrow[4] = {0.f, 0.f, 0.f, 0.f};
  int ntiles = q0 / 64 + 1; // causal: only kv tiles with kv0 <= q0+15
  for (int kt = 0; kt < ntiles; kt++) {
    int kv0 = kt * 64;
    floatx4 sf[4];
#pragma unroll
    for (int nt = 0; nt < 4; nt++) {
      const __bf16* kp = Kh + (size_t)(kv0 + nt * 16 + l15) * HD_ + quad * 8;
      bfx8 kf0 = *(const bfx8*)kp;
      bfx8 kf1 = *(const bfx8*)(kp + 32);
      floatx4 z = {0.f, 0.f, 0.f, 0.f};
      z = __builtin_amdgcn_mfma_f32_16x16x32_bf16(qf0, kf0, z, 0, 0, 0);
      sf[nt] = __builtin_amdgcn_mfma_f32_16x16x32_bf16(qf1, kf1, z, 0, 0, 0);
    }
    bool needmask = (kv0 + 63 > q0);
    float cm[4] = {-1e30f, -1e30f, -1e30f, -1e30f};
#pragma unroll
    for (int nt = 0; nt < 4; nt++)
#pragma unroll
      for (int r = 0; r < 4; r++) {
        float sv = sf[nt][r] * 0.125f; // 1/sqrt(64)
        if (needmask) {
          int col = kv0 + nt * 16 + l15;
          int row = q0 + quad * 4 + r;
          if (col > row) sv = -1e30f;
        }
        sf[nt][r] = sv;
        cm[r] = fmaxf(cm[r], sv);
      }
#pragma unroll
    for (int r = 0; r < 4; r++) {
      cm[r] = fmaxf(cm[r], __shfl_xor(cm[r], 1));
      cm[r] = fmaxf(cm[r], __shfl_xor(cm[r], 2));
      cm[r] = fmaxf(cm[r], __shfl_xor(cm[r], 4));
      cm[r] = fmaxf(cm[r], __shfl_xor(cm[r], 8));
    }
    float alpha[4], psum[4];
#pragma unroll
    for (int r = 0; r < 4; r++) {
      float mn = fmaxf(mrow[r], cm[r]);
      alpha[r] = __expf(mrow[r] - mn);
      mrow[r] = mn;
      psum[r] = 0.f;
    }
#pragma unroll
    for (int nt = 0; nt < 4; nt++)
#pragma unroll
      for (int r = 0; r < 4; r++) {
        float p = __expf(sf[nt][r] - mrow[r]);
        psum[r] += p;
        P[quad * 4 + r][nt * 16 + l15] = (__bf16)p;
      }
#pragma unroll
    for (int r = 0; r < 4; r++) {
      psum[r] += __shfl_xor(psum[r], 1);
      psum[r] += __shfl_xor(psum[r], 2);
      psum[r] += __shfl_xor(psum[r], 4);
      psum[r] += __shfl_xor(psum[r], 8);
      lrow[r] = lrow[r] * alpha[r] + psum[r];
    }
#pragma unroll
    for (int ot = 0; ot < 4; ot++)
#pragma unroll
      for (int r = 0; r < 4; r++) oacc[ot][r] *= alpha[r];
    // wave-internal LDS visibility (no __syncthreads: waves have divergent trip counts)
    asm volatile("s_waitcnt lgkmcnt(0)" ::: "memory");
    bfx8 pa0 = *(const bfx8*)&P[l15][quad * 8];
    bfx8 pa1 = *(const bfx8*)&P[l15][32 + quad * 8];
#pragma unroll
    for (int ot = 0; ot < 4; ot++) {
      const __bf16* vp = Vh + (size_t)(ot * 16 + l15) * S_ + kv0 + quad * 8;
      bfx8 vf0 = *(const bfx8*)vp;
      bfx8 vf1 = *(const bfx8*)(vp + 32);
      oacc[ot] = __builtin_amdgcn_mfma_f32_16x16x32_bf16(pa0, vf0, oacc[ot], 0, 0, 0);
      oacc[ot] = __builtin_amdgcn_mfma_f32_16x16x32_bf16(pa1, vf1, oacc[ot], 0, 0, 0);
    }
  }
#pragma unroll
  for (int ot = 0; ot < 4; ot++)
#pragma unroll
    for (int r = 0; r < 4; r++) {
      float val = oacc[ot][r] / lrow[r];
      Ob[((size_t)b * S_ + q0 + quad * 4 + r) * HQ_ + h * HD_ + ot * 16 + l15] = (__bf16)val;
    }
}

extern "C" void kernel_launch(void* const* d_in, const int* in_sizes, int n_in,
                              void* d_out, int out_size, void* d_ws, size_t ws_size,
                              hipStream_t stream) {
  const float* x   = (const float*)d_in[0];
  const float* cosT = (const float*)d_in[1];
  const float* sinT = (const float*)d_in[2];
  const float* wq  = (const float*)d_in[3];
  const float* wk  = (const float*)d_in[4];
  const float* wv  = (const float*)d_in[5];
  const float* wo  = (const float*)d_in[6];
  const float* qw  = (const float*)d_in[7];
  const float* kw  = (const float*)d_in[8];
  float* out = (float*)d_out;

  char* w = (char*)d_ws;
  __bf16* xbf   = (__bf16*)(w);                        // 4096*2048*2   = 16,777,216
  __bf16* wqkvT = (__bf16*)(w + 16777216);             // 1536*2048*2   =  6,291,456
  __bf16* woT   = (__bf16*)(w + 23068672);             // 2048*1024*2   =  4,194,304
  float*  qkv   = (float*) (w + 27262976);             // 4096*1536*4   = 25,165,824
  __bf16* Qb    = (__bf16*)(w + 52428800);             // 2*16*2048*64*2 = 8,388,608
  __bf16* Kb    = (__bf16*)(w + 60817408);             // 2*4*2048*64*2  = 2,097,152
  __bf16* VTb   = (__bf16*)(w + 62914560);             // 2,097,152
  __bf16* attn  = (__bf16*)(w + 65011712);             // 4096*1024*2   = 8,388,608  (end 73,400,320)

  // 1. cast x to bf16
  cast_f32_bf16<<<(M_ * H_ / 4 + 255) / 256, 256, 0, stream>>>(x, xbf, M_ * H_ / 4);
  // 2. transpose+cast weights to N-major (Bt = W^T)
  dim3 tb(32, 8);
  transpose_cast<<<dim3(1024 / 32, 2048 / 32), tb, 0, stream>>>(wq, wqkvT, 2048, 1024, 0,    2048);
  transpose_cast<<<dim3(256 / 32, 2048 / 32),  tb, 0, stream>>>(wk, wqkvT, 2048, 256,  1024, 2048);
  transpose_cast<<<dim3(256 / 32, 2048 / 32),  tb, 0, stream>>>(wv, wqkvT, 2048, 256,  1280, 2048);
  transpose_cast<<<dim3(2048 / 32, 1024 / 32), tb, 0, stream>>>(wo, woT,   1024, 2048, 0,    1024);
  // 3. QKV projection: [4096,2048] @ [2048,1536] -> fp32
  gemm_bf16_f32<<<dim3(NQKV_ / 128, M_ / 128), 256, 0, stream>>>(xbf, wqkvT, qkv, M_, NQKV_, H_);
  // 4. RMSNorm + RoPE + layout
  norm_rope_kernel<<<dim3(S_, B_), 256, 0, stream>>>(qkv, cosT, sinT, qw, kw, Qb, Kb, VTb);
  // 5. flash attention
  attn_kernel<<<dim3(S_ / 64, NH_, B_), 256, 0, stream>>>(Qb, Kb, VTb, attn);
  // 6. output projection: [4096,1024] @ [1024,2048] -> d_out fp32
  gemm_bf16_f32<<<dim3(H_ / 128, M_ / 128), 256, 0, stream>>>(attn, woT, out, M_, H_, HQ_);
}

// Round 2
// 319.254 us; speedup vs baseline: 1.3628x; 1.3628x over previous
//
#include <hip/hip_runtime.h>

typedef float floatx4 __attribute__((ext_vector_type(4)));
typedef __bf16 bfx8 __attribute__((ext_vector_type(8)));
typedef __bf16 bfx4 __attribute__((ext_vector_type(4)));

// Problem constants
constexpr int B_ = 2, S_ = 2048, H_ = 2048, NH_ = 16, NKV_ = 4, HD_ = 64;
constexpr int M_ = B_ * S_;               // 4096 rows
constexpr int NQKV_ = NH_ * HD_ + 2 * NKV_ * HD_; // 1536
constexpr int HQ_ = NH_ * HD_;            // 1024

// ---------------- kernel: fp32 -> bf16 cast (x4 vectorized) ----------------
__global__ __launch_bounds__(256) void cast_f32_bf16(const float* __restrict__ src,
                                                     __bf16* __restrict__ dst, int n4) {
  int i = blockIdx.x * 256 + threadIdx.x;
  if (i >= n4) return;
  float4 v = ((const float4*)src)[i];
  bfx4 o;
  o[0] = (__bf16)v.x; o[1] = (__bf16)v.y; o[2] = (__bf16)v.z; o[3] = (__bf16)v.w;
  ((bfx4*)dst)[i] = o;
}

// ---------------- kernel: transpose + cast: dst[n+off][k] = src[k][n] ----------------
__global__ __launch_bounds__(256) void transpose_cast(const float* __restrict__ src,
                                                      __bf16* __restrict__ dst,
                                                      int K, int N, int dstOff, int dstPitch) {
  __shared__ float tile[32][33];
  int n0 = blockIdx.x * 32, k0 = blockIdx.y * 32;
  int tx = threadIdx.x, ty = threadIdx.y; // block (32,8)
#pragma unroll
  for (int r = 0; r < 32; r += 8)
    tile[ty + r][tx] = src[(size_t)(k0 + ty + r) * N + n0 + tx];
  __syncthreads();
#pragma unroll
  for (int r = 0; r < 32; r += 8)
    dst[(size_t)(n0 + ty + r + dstOff) * dstPitch + k0 + tx] = (__bf16)tile[tx][ty + r];
}

// ---------------- kernel: bf16 MFMA GEMM. A: MxK row-major, Bt: NxK row-major, C: MxN fp32
// 128x128 block tile, BK=64, 4 waves in 2x2, each wave 64x64 (4x4 MFMA 16x16x32 tiles).
__global__ __launch_bounds__(256) void gemm_bf16_f32(const __bf16* __restrict__ A,
                                                     const __bf16* __restrict__ Bt,
                                                     float* __restrict__ C,
                                                     int M, int N, int K) {
  __shared__ __align__(16) __bf16 As[128][72]; // pad 64->72 (+16B): bank stride 4 -> 2-way (free)
  __shared__ __align__(16) __bf16 Bs[128][72];
  int wid = threadIdx.x >> 6, lane = threadIdx.x & 63;
  int l15 = lane & 15, quad = lane >> 4;
  int wm = (wid >> 1) * 64, wn = (wid & 1) * 64;
  int m0 = blockIdx.y * 128, n0 = blockIdx.x * 128;
  floatx4 acc[4][4] = {};
  for (int kb = 0; kb < K; kb += 64) {
#pragma unroll
    for (int i = 0; i < 4; i++) {
      int c = i * 256 + threadIdx.x;
      int r = c >> 3, col = (c & 7) * 8;
      *(bfx8*)&As[r][col] = *(const bfx8*)&A[(size_t)(m0 + r) * K + kb + col];
      *(bfx8*)&Bs[r][col] = *(const bfx8*)&Bt[(size_t)(n0 + r) * K + kb + col];
    }
    __syncthreads();
#pragma unroll
    for (int kk = 0; kk < 64; kk += 32) {
      bfx8 af[4], bfr[4];
#pragma unroll
      for (int mi = 0; mi < 4; mi++)
        af[mi] = *(const bfx8*)&As[wm + mi * 16 + l15][kk + quad * 8];
#pragma unroll
      for (int ni = 0; ni < 4; ni++)
        bfr[ni] = *(const bfx8*)&Bs[wn + ni * 16 + l15][kk + quad * 8];
#pragma unroll
      for (int mi = 0; mi < 4; mi++)
#pragma unroll
        for (int ni = 0; ni < 4; ni++)
          acc[mi][ni] = __builtin_amdgcn_mfma_f32_16x16x32_bf16(af[mi], bfr[ni], acc[mi][ni], 0, 0, 0);
    }
    __syncthreads();
  }
#pragma unroll
  for (int mi = 0; mi < 4; mi++)
#pragma unroll
    for (int ni = 0; ni < 4; ni++) {
      int row = m0 + wm + mi * 16 + quad * 4;
      int coln = n0 + wn + ni * 16 + l15;
#pragma unroll
      for (int r = 0; r < 4; r++)
        C[(size_t)(row + r) * N + coln] = acc[mi][ni][r];
    }
}

// ---------------- kernel: RMSNorm + RoPE on q/k, cast+layout for attention ----------------
__global__ __launch_bounds__(256) void norm_rope_kernel(const float* __restrict__ qkv,
                                                        const float* __restrict__ cosT,
                                                        const float* __restrict__ sinT,
                                                        const float* __restrict__ qw,
                                                        const float* __restrict__ kw,
                                                        __bf16* __restrict__ Qo,
                                                        __bf16* __restrict__ Ko,
                                                        __bf16* __restrict__ VTo) {
  int s = blockIdx.x, b = blockIdx.y;
  int wid = threadIdx.x >> 6, lane = threadIdx.x & 63;
  const float* rowp = qkv + (size_t)(b * S_ + s) * NQKV_;
  float c = cosT[s * HD_ + lane];
  float sn = sinT[s * HD_ + lane];
#pragma unroll
  for (int it = 0; it < 5; it++) {
    int hh = it * 4 + wid; // 0..15 q heads, 16..19 k heads
    float v = rowp[hh * 64 + lane];
    float ss = v * v;
#pragma unroll
    for (int off = 1; off < 64; off <<= 1) ss += __shfl_xor(ss, off);
    float rs = rsqrtf(ss * (1.0f / 64.0f) + 1e-6f);
    const float* w = (hh < 16) ? qw : kw;
    float nv = v * rs * w[lane];
    float other = __shfl_xor(nv, 32);
    float rot = (lane < 32) ? -other : other; // rotate_half
    float outv = nv * c + rot * sn;
    if (hh < 16)
      Qo[(((size_t)b * NH_ + hh) * S_ + s) * HD_ + lane] = (__bf16)outv;
    else
      Ko[(((size_t)b * NKV_ + (hh - 16)) * S_ + s) * HD_ + lane] = (__bf16)outv;
  }
  {
    float v = rowp[(20 + wid) * 64 + lane];
    VTo[(((size_t)b * NKV_ + wid) * HD_ + lane) * S_ + s] = (__bf16)v;
  }
}

// ---------------- kernel: flash attention (causal, GQA), balanced pairing ----------------
// grid (S/128, NH, B), block 512 (8 waves). Waves 0-3 -> q-tile x, waves 4-7 -> q-tile 31-x.
// Work per block = (x+1) + (32-x) = 33 kv-tiles uniformly => perfect balance on any CU mapping.
// Softmax uses fixed m=0: post-RMSNorm |q|=|k|=8 exactly => |s|<=8, exp(s)<=2981, safe in fp32.
__global__ __launch_bounds__(512, 4) void attn_kernel(const __bf16* __restrict__ Q,
                                                      const __bf16* __restrict__ Kc,
                                                      const __bf16* __restrict__ VT,
                                                      __bf16* __restrict__ Ob) {
  int x = blockIdx.x, h = blockIdx.y, b = blockIdx.z;
  int wid = threadIdx.x >> 6, lane = threadIdx.x & 63;
  int l15 = lane & 15, quad = lane >> 4;
  int sub = wid & 3;
  int qt = (wid < 4) ? x : (31 - x);
  int q0 = qt * 64 + sub * 16;
  int kvh = h >> 2; // N_REP = 4
  const __bf16* Qh = Q + (((size_t)b * NH_ + h) * S_ + q0) * HD_;
  const __bf16* Kh = Kc + (((size_t)b * NKV_ + kvh) * S_) * HD_;
  const __bf16* Vh = VT + (((size_t)b * NKV_ + kvh) * HD_) * S_;
  __shared__ __align__(16) __bf16 Pst[8][16][72]; // per-wave P staging (C-layout -> A-layout)
  __bf16 (*P)[72] = Pst[wid];

  bfx8 qf0, qf1;
  {
    const __bf16* qp = Qh + l15 * HD_ + quad * 8;
    qf0 = *(const bfx8*)qp;
    qf1 = *(const bfx8*)(qp + 32);
  }
  floatx4 oacc[4] = {};
  float psum[4] = {0.f, 0.f, 0.f, 0.f};
  int ntiles = qt + 1; // causal
  for (int kt = 0; kt < ntiles; kt++) {
    int kv0 = kt * 64;
    bool diag = (kt == qt);                 // wave-uniform
    int ntmax = diag ? sub : 3;             // nt > sub on diagonal tile is fully masked
    floatx4 sf[4];
#pragma unroll 4
    for (int nt = 0; nt <= ntmax; nt++) {
      const __bf16* kp = Kh + (size_t)(kv0 + nt * 16 + l15) * HD_ + quad * 8;
      bfx8 kf0 = *(const bfx8*)kp;
      bfx8 kf1 = *(const bfx8*)(kp + 32);
      floatx4 z = {0.f, 0.f, 0.f, 0.f};
      z = __builtin_amdgcn_mfma_f32_16x16x32_bf16(qf0, kf0, z, 0, 0, 0);
      sf[nt] = __builtin_amdgcn_mfma_f32_16x16x32_bf16(qf1, kf1, z, 0, 0, 0);
    }
    // prefetch V fragments (independent of softmax) before the LDS fence
    bfx8 vf0[4], vf1[4];
#pragma unroll
    for (int ot = 0; ot < 4; ot++) {
      const __bf16* vp = Vh + (size_t)(ot * 16 + l15) * S_ + kv0 + quad * 8;
      vf0[ot] = *(const bfx8*)vp;
      vf1[ot] = *(const bfx8*)(vp + 32);
    }
    // softmax numerator with fixed m=0; defer the l-reduction to the end
#pragma unroll 4
    for (int nt = 0; nt <= ntmax; nt++) {
      bool edge = diag && (nt == sub);
#pragma unroll
      for (int r = 0; r < 4; r++) {
        float p = __expf(sf[nt][r] * 0.125f); // 1/sqrt(64)
        if (edge) {
          int col = nt * 16 + l15;            // both relative to tile origin (kv0 == qt*64 here)
          int row = sub * 16 + quad * 4 + r;
          if (col > row) p = 0.f;
        }
        psum[r] += p;
        P[quad * 4 + r][nt * 16 + l15] = (__bf16)p;
      }
    }
#pragma unroll 4
    for (int nt = ntmax + 1; nt < 4; nt++)
#pragma unroll
      for (int r = 0; r < 4; r++)
        P[quad * 4 + r][nt * 16 + l15] = (__bf16)0.f;
    // wave-internal LDS visibility (waves have divergent trip counts; no __syncthreads)
    asm volatile("s_waitcnt lgkmcnt(0)" ::: "memory");
    bfx8 pa0 = *(const bfx8*)&P[l15][quad * 8];
    bfx8 pa1 = *(const bfx8*)&P[l15][32 + quad * 8];
#pragma unroll
    for (int ot = 0; ot < 4; ot++) {
      oacc[ot] = __builtin_amdgcn_mfma_f32_16x16x32_bf16(pa0, vf0[ot], oacc[ot], 0, 0, 0);
      oacc[ot] = __builtin_amdgcn_mfma_f32_16x16x32_bf16(pa1, vf1[ot], oacc[ot], 0, 0, 0);
    }
  }
  // single deferred l-reduction across the 16 col-lanes
#pragma unroll
  for (int r = 0; r < 4; r++) {
    psum[r] += __shfl_xor(psum[r], 1);
    psum[r] += __shfl_xor(psum[r], 2);
    psum[r] += __shfl_xor(psum[r], 4);
    psum[r] += __shfl_xor(psum[r], 8);
  }
#pragma unroll
  for (int ot = 0; ot < 4; ot++)
#pragma unroll
    for (int r = 0; r < 4; r++) {
      float val = oacc[ot][r] / psum[r];
      Ob[((size_t)b * S_ + q0 + quad * 4 + r) * HQ_ + h * HD_ + ot * 16 + l15] = (__bf16)val;
    }
}

extern "C" void kernel_launch(void* const* d_in, const int* in_sizes, int n_in,
                              void* d_out, int out_size, void* d_ws, size_t ws_size,
                              hipStream_t stream) {
  const float* x   = (const float*)d_in[0];
  const float* cosT = (const float*)d_in[1];
  const float* sinT = (const float*)d_in[2];
  const float* wq  = (const float*)d_in[3];
  const float* wk  = (const float*)d_in[4];
  const float* wv  = (const float*)d_in[5];
  const float* wo  = (const float*)d_in[6];
  const float* qw  = (const float*)d_in[7];
  const float* kw  = (const float*)d_in[8];
  float* out = (float*)d_out;

  char* w = (char*)d_ws;
  __bf16* xbf   = (__bf16*)(w);                        // 16,777,216
  __bf16* wqkvT = (__bf16*)(w + 16777216);             //  6,291,456
  __bf16* woT   = (__bf16*)(w + 23068672);             //  4,194,304
  float*  qkv   = (float*) (w + 27262976);             // 25,165,824
  __bf16* Qb    = (__bf16*)(w + 52428800);             //  8,388,608
  __bf16* Kb    = (__bf16*)(w + 60817408);             //  2,097,152
  __bf16* VTb   = (__bf16*)(w + 62914560);             //  2,097,152
  __bf16* attn  = (__bf16*)(w + 65011712);             //  8,388,608 (end 73,400,320)

  cast_f32_bf16<<<(M_ * H_ / 4 + 255) / 256, 256, 0, stream>>>(x, xbf, M_ * H_ / 4);
  dim3 tb(32, 8);
  transpose_cast<<<dim3(1024 / 32, 2048 / 32), tb, 0, stream>>>(wq, wqkvT, 2048, 1024, 0,    2048);
  transpose_cast<<<dim3(256 / 32, 2048 / 32),  tb, 0, stream>>>(wk, wqkvT, 2048, 256,  1024, 2048);
  transpose_cast<<<dim3(256 / 32, 2048 / 32),  tb, 0, stream>>>(wv, wqkvT, 2048, 256,  1280, 2048);
  transpose_cast<<<dim3(2048 / 32, 1024 / 32), tb, 0, stream>>>(wo, woT,   1024, 2048, 0,    1024);
  gemm_bf16_f32<<<dim3(NQKV_ / 128, M_ / 128), 256, 0, stream>>>(xbf, wqkvT, qkv, M_, NQKV_, H_);
  norm_rope_kernel<<<dim3(S_, B_), 256, 0, stream>>>(qkv, cosT, sinT, qw, kw, Qb, Kb, VTb);
  attn_kernel<<<dim3(S_ / 128, NH_, B_), 512, 0, stream>>>(Qb, Kb, VTb, attn);
  gemm_bf16_f32<<<dim3(H_ / 128, M_ / 128), 256, 0, stream>>>(attn, woT, out, M_, H_, HQ_);
}